// Round 2
// baseline (129.097 us; speedup 1.0000x reference)
//
#include <hip/hip_runtime.h>
#include <hip/hip_bf16.h>
#include <math.h>

constexpr int kNumSeqs      = 64;
constexpr int kNumHeads     = 32;
constexpr int kNumKVHeads   = 8;
constexpr int kHeadDim      = 128;
constexpr int kGQA          = kNumHeads / kNumKVHeads;   // 4
constexpr int kKVBlock      = 16;
constexpr int kMaxSeqlen    = 1024;
constexpr int kBlocksPerSeq = kMaxSeqlen / kKVBlock;     // 64
constexpr float kScale      = 0.08838834764831845f;      // 1/sqrt(128)
constexpr float kEps        = 1e-6f;

__launch_bounds__(512)
__global__ void paged_attn_fused(
    const float* __restrict__ q,
    const float* __restrict__ k,
    const float* __restrict__ v,
    const float* __restrict__ k_cache,
    const float* __restrict__ v_cache,
    const float* __restrict__ qw,
    const float* __restrict__ kw,
    const float* __restrict__ cos_cache,
    const float* __restrict__ sin_cache,
    const int*   __restrict__ position,
    const int*   __restrict__ block_tables,
    const int*   __restrict__ context_lens,
    float* __restrict__ out)
{
  const int s    = blockIdx.x >> 3;
  const int h    = blockIdx.x & 7;
  const int tid  = threadIdx.x;
  const int wave = tid >> 6;
  const int lane = tid & 63;

  __shared__ __align__(16) float sc[kGQA][kMaxSeqlen];      // scores, then probs (in place)
  __shared__ __align__(16) float q_lds[kGQA][kHeadDim];     // normed+roped+scaled q
  __shared__ __align__(16) float kn_lds[kHeadDim];          // new k (normed+roped)
  __shared__ __align__(16) float vn_lds[kHeadDim];          // new v (raw)
  __shared__ int   bt_lds[kBlocksPerSeq];
  __shared__ float red[8][kGQA];
  __shared__ float mfin[kGQA];
  __shared__ float inv_l[kGQA];
  __shared__ __align__(16) float outp[8][kGQA][kHeadDim];

  const int ctx = context_lens[s];
  const int pos = position[s];          // == ctx - 1 by construction

  // ---------------- prologue: RMSNorm + RoPE, stage new k/v + block table ----------------
  if (wave < 4) {
    const int g = wave;
    const float* qrow = q + (size_t)s * (kNumHeads * kHeadDim) + (h * kGQA + g) * kHeadDim;
    float x1 = qrow[lane];
    float x2 = qrow[lane + 64];
    float ss = x1 * x1 + x2 * x2;
    for (int off = 32; off >= 1; off >>= 1) ss += __shfl_xor(ss, off);
    const float r = rsqrtf(ss * (1.0f / kHeadDim) + kEps);
    x1 *= r * qw[lane];
    x2 *= r * qw[lane + 64];
    const float c  = cos_cache[pos * 64 + lane];
    const float sn = sin_cache[pos * 64 + lane];
    q_lds[g][lane]      = (x1 * c - x2 * sn) * kScale;
    q_lds[g][lane + 64] = (x2 * c + x1 * sn) * kScale;
  } else if (wave == 4) {
    const float* krow = k + (size_t)s * (kNumKVHeads * kHeadDim) + h * kHeadDim;
    float x1 = krow[lane];
    float x2 = krow[lane + 64];
    float ss = x1 * x1 + x2 * x2;
    for (int off = 32; off >= 1; off >>= 1) ss += __shfl_xor(ss, off);
    const float r = rsqrtf(ss * (1.0f / kHeadDim) + kEps);
    x1 *= r * kw[lane];
    x2 *= r * kw[lane + 64];
    const float c  = cos_cache[pos * 64 + lane];
    const float sn = sin_cache[pos * 64 + lane];
    kn_lds[lane]      = x1 * c - x2 * sn;
    kn_lds[lane + 64] = x2 * c + x1 * sn;
  } else if (wave == 5) {
    const float* vrow = v + (size_t)s * (kNumKVHeads * kHeadDim) + h * kHeadDim;
    vn_lds[lane]      = vrow[lane];
    vn_lds[lane + 64] = vrow[lane + 64];
  } else if (wave == 6) {
    if (lane < kBlocksPerSeq)
      bt_lds[lane] = block_tables[s * kBlocksPerSeq + lane];
  }
  __syncthreads();

  const int half = lane >> 5;       // which of the 2 positions this lane serves
  const int l    = lane & 31;       // dim chunk: floats [4l, 4l+4)

  float4 qf[kGQA];
  #pragma unroll
  for (int g = 0; g < kGQA; ++g)
    qf[g] = *(const float4*)&q_lds[g][4 * l];

  const int npairs = (ctx + 1) >> 1;
  const int ppw    = (npairs + 7) >> 3;
  const int pbeg   = wave * ppw;
  const int pend   = min(pbeg + ppw, npairs);

  // ---------------- pass 1: scores = (q*scale) . K ----------------
  for (int p = pbeg; p < pend; ++p) {
    const int  n     = 2 * p + half;
    const bool valid = (n < ctx);
    const int  nn    = valid ? n : (ctx - 1);
    const int  blk   = bt_lds[nn >> 4];
    const float* krow =
        k_cache + (((size_t)blk * kKVBlock + (nn & 15)) * kNumKVHeads + h) * kHeadDim;
    float4 kv = *(const float4*)(krow + 4 * l);
    if (nn == pos) kv = *(const float4*)&kn_lds[4 * l];   // virtual cache insert (new k)
    float sg[kGQA];
    #pragma unroll
    for (int g = 0; g < kGQA; ++g)
      sg[g] = qf[g].x * kv.x + qf[g].y * kv.y + qf[g].z * kv.z + qf[g].w * kv.w;
    #pragma unroll
    for (int off = 16; off >= 1; off >>= 1) {
      #pragma unroll
      for (int g = 0; g < kGQA; ++g) sg[g] += __shfl_xor(sg[g], off);
    }
    if (l == 0 && valid) {
      #pragma unroll
      for (int g = 0; g < kGQA; ++g) sc[g][n] = sg[g];
    }
  }
  __syncthreads();

  // ---------------- softmax: max ----------------
  float mg[kGQA];
  #pragma unroll
  for (int g = 0; g < kGQA; ++g) mg[g] = -3.0e38f;
  for (int n = tid; n < ctx; n += 512) {
    #pragma unroll
    for (int g = 0; g < kGQA; ++g) mg[g] = fmaxf(mg[g], sc[g][n]);
  }
  #pragma unroll
  for (int off = 32; off >= 1; off >>= 1) {
    #pragma unroll
    for (int g = 0; g < kGQA; ++g) mg[g] = fmaxf(mg[g], __shfl_xor(mg[g], off));
  }
  if (lane == 0) {
    #pragma unroll
    for (int g = 0; g < kGQA; ++g) red[wave][g] = mg[g];
  }
  __syncthreads();
  if (tid < kGQA) {
    float m = red[0][tid];
    #pragma unroll
    for (int w = 1; w < 8; ++w) m = fmaxf(m, red[w][tid]);
    mfin[tid] = m;
  }
  __syncthreads();

  // ---------------- softmax: exp + sum (probs in place, unnormalized) ----------------
  float mloc[kGQA], lg[kGQA];
  #pragma unroll
  for (int g = 0; g < kGQA; ++g) { mloc[g] = mfin[g]; lg[g] = 0.0f; }
  for (int n = tid; n < ctx; n += 512) {
    #pragma unroll
    for (int g = 0; g < kGQA; ++g) {
      const float pv = __expf(sc[g][n] - mloc[g]);
      sc[g][n] = pv;
      lg[g] += pv;
    }
  }
  #pragma unroll
  for (int off = 32; off >= 1; off >>= 1) {
    #pragma unroll
    for (int g = 0; g < kGQA; ++g) lg[g] += __shfl_xor(lg[g], off);
  }
  if (lane == 0) {
    #pragma unroll
    for (int g = 0; g < kGQA; ++g) red[wave][g] = lg[g];
  }
  __syncthreads();
  if (tid < kGQA) {
    float t = 0.0f;
    #pragma unroll
    for (int w = 0; w < 8; ++w) t += red[w][tid];
    inv_l[tid] = 1.0f / t;   // consumed only after the post-pass-2 barrier
  }

  // ---------------- pass 2: probs @ V ----------------
  float4 acc[kGQA];
  #pragma unroll
  for (int g = 0; g < kGQA; ++g) acc[g] = make_float4(0.f, 0.f, 0.f, 0.f);
  for (int p = pbeg; p < pend; ++p) {
    const int  n     = 2 * p + half;
    const bool valid = (n < ctx);
    const int  nn    = valid ? n : (ctx - 1);
    const int  blk   = bt_lds[nn >> 4];
    const float* vrow =
        v_cache + (((size_t)blk * kKVBlock + (nn & 15)) * kNumKVHeads + h) * kHeadDim;
    float4 vv = *(const float4*)(vrow + 4 * l);
    if (nn == pos) vv = *(const float4*)&vn_lds[4 * l];   // virtual cache insert (new v)
    #pragma unroll
    for (int g = 0; g < kGQA; ++g) {
      const float pr = valid ? sc[g][n] : 0.0f;
      acc[g].x += pr * vv.x;
      acc[g].y += pr * vv.y;
      acc[g].z += pr * vv.z;
      acc[g].w += pr * vv.w;
    }
  }
  #pragma unroll
  for (int g = 0; g < kGQA; ++g) {
    acc[g].x += __shfl_xor(acc[g].x, 32);
    acc[g].y += __shfl_xor(acc[g].y, 32);
    acc[g].z += __shfl_xor(acc[g].z, 32);
    acc[g].w += __shfl_xor(acc[g].w, 32);
  }
  if (half == 0) {
    #pragma unroll
    for (int g = 0; g < kGQA; ++g)
      *(float4*)&outp[wave][g][4 * l] = acc[g];
  }
  __syncthreads();

  // ---------------- final: cross-wave reduce, normalize, f32 store ----------------
  {
    const int g = tid >> 7;
    const int d = tid & 127;
    float sum = 0.0f;
    #pragma unroll
    for (int w = 0; w < 8; ++w) sum += outp[w][g][d];
    out[(size_t)s * (kNumHeads * kHeadDim) + (h * kGQA + g) * kHeadDim + d] =
        sum * inv_l[g];
  }
}

extern "C" void kernel_launch(void* const* d_in, const int* in_sizes, int n_in,
                              void* d_out, int out_size, void* d_ws, size_t ws_size,
                              hipStream_t stream) {
  const float* q            = (const float*)d_in[0];
  const float* k            = (const float*)d_in[1];
  const float* v            = (const float*)d_in[2];
  const float* k_cache      = (const float*)d_in[3];
  const float* v_cache      = (const float*)d_in[4];
  const float* qw           = (const float*)d_in[5];
  const float* kw           = (const float*)d_in[6];
  const float* cosc         = (const float*)d_in[7];
  const float* sinc         = (const float*)d_in[8];
  const int*   position     = (const int*)d_in[9];
  // d_in[10] = slot_mapping: redundant (slot == seq*1024 + position under this block table)
  const int*   block_tables = (const int*)d_in[11];
  const int*   context_lens = (const int*)d_in[12];
  float* out                = (float*)d_out;

  dim3 grid(kNumSeqs * kNumKVHeads);
  dim3 block(512);
  hipLaunchKernelGGL(paged_attn_fused, grid, block, 0, stream,
                     q, k, v, k_cache, v_cache, qw, kw, cosc, sinc,
                     position, block_tables, context_lens, out);
}

// Round 3
// 109.632 us; speedup vs baseline: 1.1776x; 1.1776x over previous
//
#include <hip/hip_runtime.h>
#include <math.h>

constexpr int kNumSeqs      = 64;
constexpr int kNumHeads     = 32;
constexpr int kNumKVHeads   = 8;
constexpr int kHeadDim      = 128;
constexpr int kGQA          = 4;       // 32/8
constexpr int kKVBlock      = 16;
constexpr int kMaxSeqlen    = 1024;
constexpr int kBlocksPerSeq = 64;
constexpr int kPart         = 4;       // split-K partitions
constexpr int kPartSize     = 256;     // positions per partition
constexpr float kScale      = 0.08838834764831845f;  // 1/sqrt(128)
constexpr float kEps        = 1e-6f;

// ws layout (floats):
//   acc : [s][h][part][g][128] -> 64*8*4*4*128 = 1,048,576
//   m   : [s][h][part][g]      -> 8,192 @ 1,048,576
//   l   : [s][h][part][g]      -> 8,192 @ 1,056,768
constexpr size_t kAccElems = (size_t)kNumSeqs * kNumKVHeads * kPart * kGQA * kHeadDim;
constexpr size_t kMOff     = kAccElems;
constexpr size_t kLOff     = kAccElems + (size_t)kNumSeqs * kNumKVHeads * kPart * kGQA;

__launch_bounds__(256)
__global__ void paged_attn_part(
    const float* __restrict__ q,
    const float* __restrict__ k,
    const float* __restrict__ v,
    const float* __restrict__ k_cache,
    const float* __restrict__ v_cache,
    const float* __restrict__ qw,
    const float* __restrict__ kw,
    const float* __restrict__ cos_cache,
    const float* __restrict__ sin_cache,
    const int*   __restrict__ position,
    const int*   __restrict__ block_tables,
    const int*   __restrict__ context_lens,
    float* __restrict__ ws)
{
  const int bx   = blockIdx.x;
  const int s    = bx >> 5;          // 8 heads * 4 parts = 32 per seq
  const int h    = (bx >> 2) & 7;
  const int part = bx & 3;
  const int tid  = threadIdx.x;
  const int wave = tid >> 6;
  const int lane = tid & 63;

  const int ctx = context_lens[s];
  const int pos = position[s];                 // == ctx-1
  const int n0  = part * kPartSize;

  float* accw = ws + ((((size_t)s * kNumKVHeads + h) * kPart + part) * kGQA) * kHeadDim;
  float* mw   = ws + kMOff + (((size_t)s * kNumKVHeads + h) * kPart + part) * kGQA;
  float* lw   = ws + kLOff + (((size_t)s * kNumKVHeads + h) * kPart + part) * kGQA;

  if (n0 >= ctx) {                              // empty partition: neutral element
    for (int e = tid; e < kGQA * kHeadDim; e += 256) accw[e] = 0.0f;
    if (tid < kGQA) { mw[tid] = -3.0e38f; lw[tid] = 0.0f; }
    return;
  }
  const int nEnd     = min(n0 + kPartSize, ctx);
  const int cnt      = nEnd - n0;               // 1..256
  const int posLocal = pos - n0;                // in [0,256) only for last live partition
  const bool haspos  = (posLocal >= 0) && (posLocal < cnt);

  __shared__ __align__(16) float sc[kGQA][kPartSize];     // scores -> probs (unnormalized)
  __shared__ __align__(16) float q_lds[kGQA][kHeadDim];
  __shared__ __align__(16) float kn_lds[kHeadDim];
  __shared__ __align__(16) float vn_lds[kHeadDim];
  __shared__ int   bt_lds[kPartSize / kKVBlock];          // 16 blocks
  __shared__ float red[4][kGQA];
  __shared__ float mfin[kGQA];
  __shared__ float lfin[kGQA];
  __shared__ __align__(16) float outp[4][kGQA][kHeadDim];

  // ---------------- prologue ----------------
  {
    const int g = wave;
    const float* qrow = q + (size_t)s * (kNumHeads * kHeadDim) + (h * kGQA + g) * kHeadDim;
    float x1 = qrow[lane];
    float x2 = qrow[lane + 64];
    float ss = x1 * x1 + x2 * x2;
    for (int off = 32; off >= 1; off >>= 1) ss += __shfl_xor(ss, off);
    const float r = rsqrtf(ss * (1.0f / kHeadDim) + kEps);
    x1 *= r * qw[lane];
    x2 *= r * qw[lane + 64];
    const float c  = cos_cache[pos * 64 + lane];
    const float sn = sin_cache[pos * 64 + lane];
    q_lds[g][lane]      = (x1 * c - x2 * sn) * kScale;
    q_lds[g][lane + 64] = (x2 * c + x1 * sn) * kScale;
  }
  if (wave == 0) {
    const float* krow = k + (size_t)s * (kNumKVHeads * kHeadDim) + h * kHeadDim;
    float x1 = krow[lane];
    float x2 = krow[lane + 64];
    float ss = x1 * x1 + x2 * x2;
    for (int off = 32; off >= 1; off >>= 1) ss += __shfl_xor(ss, off);
    const float r = rsqrtf(ss * (1.0f / kHeadDim) + kEps);
    x1 *= r * kw[lane];
    x2 *= r * kw[lane + 64];
    const float c  = cos_cache[pos * 64 + lane];
    const float sn = sin_cache[pos * 64 + lane];
    kn_lds[lane]      = x1 * c - x2 * sn;
    kn_lds[lane + 64] = x2 * c + x1 * sn;
  } else if (wave == 1) {
    const float* vrow = v + (size_t)s * (kNumKVHeads * kHeadDim) + h * kHeadDim;
    vn_lds[lane]      = vrow[lane];
    vn_lds[lane + 64] = vrow[lane + 64];
  } else if (wave == 2) {
    if (lane < kPartSize / kKVBlock)
      bt_lds[lane] = block_tables[s * kBlocksPerSeq + part * (kPartSize / kKVBlock) + lane];
  }
  __syncthreads();

  const int half = lane >> 5;
  const int l    = lane & 31;

  float4 qf[kGQA];
  #pragma unroll
  for (int g = 0; g < kGQA; ++g)
    qf[g] = *(const float4*)&q_lds[g][4 * l];

  const int npairs = (cnt + 1) >> 1;
  const int ppw    = (npairs + 3) >> 2;
  const int pbeg   = wave * ppw;
  const int pend   = min(pbeg + ppw, npairs);

  // ---------------- pass 1: scores ----------------
  #pragma unroll 2
  for (int p = pbeg; p < pend; ++p) {
    const int  nl    = 2 * p + half;              // local position
    const bool valid = (nl < cnt);
    const int  nn    = valid ? nl : (cnt - 1);
    const int  blk   = bt_lds[nn >> 4];
    const float* krow =
        k_cache + (((size_t)blk * kKVBlock + (nn & 15)) * kNumKVHeads + h) * kHeadDim;
    float4 kv = *(const float4*)(krow + 4 * l);
    if (haspos && nn == posLocal) kv = *(const float4*)&kn_lds[4 * l];  // virtual insert
    float sg[kGQA];
    #pragma unroll
    for (int g = 0; g < kGQA; ++g)
      sg[g] = qf[g].x * kv.x + qf[g].y * kv.y + qf[g].z * kv.z + qf[g].w * kv.w;
    #pragma unroll
    for (int off = 16; off >= 1; off >>= 1) {
      #pragma unroll
      for (int g = 0; g < kGQA; ++g) sg[g] += __shfl_xor(sg[g], off);
    }
    if (l == 0 && valid) {
      #pragma unroll
      for (int g = 0; g < kGQA; ++g) sc[g][nl] = sg[g];
    }
  }
  __syncthreads();

  // ---------------- local softmax: max ----------------
  float mg[kGQA];
  #pragma unroll
  for (int g = 0; g < kGQA; ++g) mg[g] = -3.0e38f;
  for (int n = tid; n < cnt; n += 256) {
    #pragma unroll
    for (int g = 0; g < kGQA; ++g) mg[g] = fmaxf(mg[g], sc[g][n]);
  }
  #pragma unroll
  for (int off = 32; off >= 1; off >>= 1) {
    #pragma unroll
    for (int g = 0; g < kGQA; ++g) mg[g] = fmaxf(mg[g], __shfl_xor(mg[g], off));
  }
  if (lane == 0) {
    #pragma unroll
    for (int g = 0; g < kGQA; ++g) red[wave][g] = mg[g];
  }
  __syncthreads();
  if (tid < kGQA) {
    float m = red[0][tid];
    #pragma unroll
    for (int w = 1; w < 4; ++w) m = fmaxf(m, red[w][tid]);
    mfin[tid] = m;
  }
  __syncthreads();

  // ---------------- local softmax: exp + sum ----------------
  float mloc[kGQA], lg[kGQA];
  #pragma unroll
  for (int g = 0; g < kGQA; ++g) { mloc[g] = mfin[g]; lg[g] = 0.0f; }
  for (int n = tid; n < cnt; n += 256) {
    #pragma unroll
    for (int g = 0; g < kGQA; ++g) {
      const float pv = __expf(sc[g][n] - mloc[g]);
      sc[g][n] = pv;
      lg[g] += pv;
    }
  }
  #pragma unroll
  for (int off = 32; off >= 1; off >>= 1) {
    #pragma unroll
    for (int g = 0; g < kGQA; ++g) lg[g] += __shfl_xor(lg[g], off);
  }
  if (lane == 0) {
    #pragma unroll
    for (int g = 0; g < kGQA; ++g) red[wave][g] = lg[g];
  }
  __syncthreads();                                 // sc complete + red complete
  if (tid < kGQA) {
    float t = 0.0f;
    #pragma unroll
    for (int w = 0; w < 4; ++w) t += red[w][tid];
    lfin[tid] = t;                                 // ordered by the post-pass-2 barrier
  }

  // ---------------- pass 2: probs @ V (unnormalized) ----------------
  float4 acc[kGQA];
  #pragma unroll
  for (int g = 0; g < kGQA; ++g) acc[g] = make_float4(0.f, 0.f, 0.f, 0.f);
  #pragma unroll 2
  for (int p = pbeg; p < pend; ++p) {
    const int  nl    = 2 * p + half;
    const bool valid = (nl < cnt);
    const int  nn    = valid ? nl : (cnt - 1);
    const int  blk   = bt_lds[nn >> 4];
    const float* vrow =
        v_cache + (((size_t)blk * kKVBlock + (nn & 15)) * kNumKVHeads + h) * kHeadDim;
    float4 vv = *(const float4*)(vrow + 4 * l);
    if (haspos && nn == posLocal) vv = *(const float4*)&vn_lds[4 * l];  // virtual insert
    #pragma unroll
    for (int g = 0; g < kGQA; ++g) {
      const float pr = valid ? sc[g][nl] : 0.0f;
      acc[g].x += pr * vv.x;
      acc[g].y += pr * vv.y;
      acc[g].z += pr * vv.z;
      acc[g].w += pr * vv.w;
    }
  }
  #pragma unroll
  for (int g = 0; g < kGQA; ++g) {
    acc[g].x += __shfl_xor(acc[g].x, 32);
    acc[g].y += __shfl_xor(acc[g].y, 32);
    acc[g].z += __shfl_xor(acc[g].z, 32);
    acc[g].w += __shfl_xor(acc[g].w, 32);
  }
  if (half == 0) {
    #pragma unroll
    for (int g = 0; g < kGQA; ++g)
      *(float4*)&outp[wave][g][4 * l] = acc[g];
  }
  __syncthreads();

  // ---------------- emit partials ----------------
  #pragma unroll
  for (int e = tid; e < kGQA * kHeadDim; e += 256) {
    const int g = e >> 7;
    const int d = e & 127;
    float sum = 0.0f;
    #pragma unroll
    for (int w = 0; w < 4; ++w) sum += outp[w][g][d];
    accw[e] = sum;
  }
  if (tid < kGQA) { mw[tid] = mfin[tid]; lw[tid] = lfin[tid]; }
}

__launch_bounds__(128)
__global__ void paged_attn_reduce(const float* __restrict__ ws,
                                  float* __restrict__ out)
{
  const int idx = blockIdx.x;          // (s*8+h)*4 + g
  const int g   = idx & 3;
  const int sh  = idx >> 2;
  const int d   = threadIdx.x;

  const float* mw = ws + kMOff + (size_t)sh * (kPart * kGQA);
  const float* lw = ws + kLOff + (size_t)sh * (kPart * kGQA);

  float m[kPart];
  #pragma unroll
  for (int p = 0; p < kPart; ++p) m[p] = mw[p * kGQA + g];
  float mstar = m[0];
  #pragma unroll
  for (int p = 1; p < kPart; ++p) mstar = fmaxf(mstar, m[p]);

  float w[kPart], lstar = 0.0f;
  #pragma unroll
  for (int p = 0; p < kPart; ++p) {
    w[p] = __expf(m[p] - mstar);
    lstar += w[p] * lw[p * kGQA + g];
  }

  float o = 0.0f;
  #pragma unroll
  for (int p = 0; p < kPart; ++p) {
    const float* accp = ws + (((size_t)sh * kPart + p) * kGQA + g) * kHeadDim;
    o += w[p] * accp[d];
  }
  const int s = sh >> 3, h = sh & 7;
  out[(size_t)s * (kNumHeads * kHeadDim) + (h * kGQA + g) * kHeadDim + d] = o / lstar;
}

extern "C" void kernel_launch(void* const* d_in, const int* in_sizes, int n_in,
                              void* d_out, int out_size, void* d_ws, size_t ws_size,
                              hipStream_t stream) {
  const float* q            = (const float*)d_in[0];
  const float* k            = (const float*)d_in[1];
  const float* v            = (const float*)d_in[2];
  const float* k_cache      = (const float*)d_in[3];
  const float* v_cache      = (const float*)d_in[4];
  const float* qw           = (const float*)d_in[5];
  const float* kw           = (const float*)d_in[6];
  const float* cosc         = (const float*)d_in[7];
  const float* sinc         = (const float*)d_in[8];
  const int*   position     = (const int*)d_in[9];
  const int*   block_tables = (const int*)d_in[11];
  const int*   context_lens = (const int*)d_in[12];
  float* out                = (float*)d_out;
  float* ws                 = (float*)d_ws;

  hipLaunchKernelGGL(paged_attn_part, dim3(kNumSeqs * kNumKVHeads * kPart), dim3(256),
                     0, stream,
                     q, k, v, k_cache, v_cache, qw, kw, cosc, sinc,
                     position, block_tables, context_lens, ws);
  hipLaunchKernelGGL(paged_attn_reduce, dim3(kNumSeqs * kNumKVHeads * kGQA), dim3(kHeadDim),
                     0, stream, ws, out);
}